// Round 10
// baseline (267.909 us; speedup 1.0000x reference)
//
#include <hip/hip_runtime.h>

#define BB 8
#define LL 2048
#define DD 256

typedef _Float16 half8 __attribute__((ext_vector_type(8)));
typedef _Float16 half4 __attribute__((ext_vector_type(4)));
typedef float floatx4 __attribute__((ext_vector_type(4)));
typedef unsigned short ushort8 __attribute__((ext_vector_type(8)));

__device__ inline unsigned short f2h(float f) {
  _Float16 h = (_Float16)f;
  return __builtin_bit_cast(unsigned short, h);
}

#define GLD16(src, ldsbase)                                                    \
  __builtin_amdgcn_global_load_lds(                                           \
      (const __attribute__((address_space(1))) unsigned int*)(src),           \
      (__attribute__((address_space(3))) unsigned int*)(ldsbase), 16, 0, 0)

// ---------------------------------------------------------------------------
// Kernel 1: fused W-convert + QKV projection (unchanged from round 9;
// measured-neutral vs v2+wcvt, keeps one fewer dispatch).
// ---------------------------------------------------------------------------
__global__ __launch_bounds__(512) void proj(
    const float* __restrict__ x, const float* __restrict__ Wq,
    const float* __restrict__ Wk, const float* __restrict__ Wv,
    unsigned short* __restrict__ Qb, unsigned short* __restrict__ Kb,
    unsigned short* __restrict__ VT) {
  __shared__ __attribute__((aligned(16))) unsigned char smem[69632];
  unsigned short* Ws = (unsigned short*)smem;
  unsigned short* tile = (unsigned short*)(smem + 32768);
  const int t = threadIdx.x;
  const int wave = t >> 6, lane = t & 63, quad = lane >> 4, m16 = lane & 15;
  const int ot = wave >> 1, p = wave & 1;
  const int l0g = blockIdx.x * 64;
  const int b = l0g >> 11, lb = l0g & 2047;

  half8 xf[2][8];
#pragma unroll
  for (int j = 0; j < 2; ++j) {
    const float* xp =
        x + (size_t)(l0g + (p * 2 + j) * 16 + m16) * DD + quad * 8;
#pragma unroll
    for (int kb = 0; kb < 8; ++kb) {
      float4 a = *(const float4*)(xp + kb * 32);
      float4 c = *(const float4*)(xp + kb * 32 + 4);
      ushort8 u = {f2h(a.x), f2h(a.y), f2h(a.z), f2h(a.w),
                   f2h(c.x), f2h(c.y), f2h(c.z), f2h(c.w)};
      xf[j][kb] = __builtin_bit_cast(half8, u);
    }
  }

  float4 wA[4], wB[4];
#define LOADW(G)                                                              \
  {                                                                           \
    const int mat_ = (G) >> 2, og_ = (G)&3;                                   \
    const float* Wm = (mat_ == 0) ? Wq : (mat_ == 1) ? Wk : Wv;               \
    _Pragma("unroll") for (int c = 0; c < 4; ++c) {                           \
      int ch = c * 512 + t, row = ch >> 5, cc = ch & 31;                      \
      const float* s = Wm + (size_t)(og_ * 64 + row) * DD + cc * 8;           \
      wA[c] = *(const float4*)s;                                              \
      wB[c] = *(const float4*)(s + 4);                                        \
    }                                                                         \
  }

  LOADW(0);
  asm volatile("" ::: "memory");

  for (int g = 0; g < 12; ++g) {
    const int mat = g >> 2, og = g & 3;
    __syncthreads();
#pragma unroll
    for (int c = 0; c < 4; ++c) {
      int ch = c * 512 + t, row = ch >> 5, cc = ch & 31;
      ushort8 u = {f2h(wA[c].x), f2h(wA[c].y), f2h(wA[c].z), f2h(wA[c].w),
                   f2h(wB[c].x), f2h(wB[c].y), f2h(wB[c].z), f2h(wB[c].w)};
      *(ushort8*)&Ws[row * 256 + ((cc ^ (row & 7)) << 3)] = u;
    }
    __syncthreads();
    if (g < 11) {
      LOADW(g + 1);
      asm volatile("" ::: "memory");
    }

    floatx4 acc[2] = {{0, 0, 0, 0}, {0, 0, 0, 0}};
    if (mat < 2) {
#pragma unroll
      for (int kb = 0; kb < 8; ++kb) {
        half8 wf = __builtin_bit_cast(
            half8, *(const ushort8*)&Ws[(ot * 16 + m16) * 256 +
                                        (((kb * 4 + quad) ^ (m16 & 7)) << 3)]);
        acc[0] = __builtin_amdgcn_mfma_f32_16x16x32_f16(xf[0][kb], wf,
                                                        acc[0], 0, 0, 0);
        acc[1] = __builtin_amdgcn_mfma_f32_16x16x32_f16(xf[1][kb], wf,
                                                        acc[1], 0, 0, 0);
      }
#pragma unroll
      for (int j = 0; j < 2; ++j)
#pragma unroll
        for (int r = 0; r < 4; ++r)
          tile[((p * 2 + j) * 16 + quad * 4 + r) * 264 + og * 64 + ot * 16 +
               m16] = f2h(acc[j][r]);
    } else {
#pragma unroll
      for (int kb = 0; kb < 8; ++kb) {
        half8 wf = __builtin_bit_cast(
            half8, *(const ushort8*)&Ws[(ot * 16 + m16) * 256 +
                                        (((kb * 4 + quad) ^ (m16 & 7)) << 3)]);
        acc[0] = __builtin_amdgcn_mfma_f32_16x16x32_f16(wf, xf[0][kb],
                                                        acc[0], 0, 0, 0);
        acc[1] = __builtin_amdgcn_mfma_f32_16x16x32_f16(wf, xf[1][kb],
                                                        acc[1], 0, 0, 0);
      }
#pragma unroll
      for (int j = 0; j < 2; ++j)
#pragma unroll
        for (int r = 0; r < 4; ++r)
          tile[(og * 64 + ot * 16 + quad * 4 + r) * 72 + (p * 2 + j) * 16 +
               m16] = f2h(acc[j][r]);
    }

    if (og == 3) {
      __syncthreads();
      if (mat < 2) {
        unsigned short* Out = mat ? Kb : Qb;
        const int row = t >> 3, c0 = (t & 7) * 8;
#pragma unroll
        for (int i = 0; i < 4; ++i) {
          ushort8 v = *(const ushort8*)&tile[row * 264 + c0 + i * 64];
          *(ushort8*)(Out + (size_t)(l0g + row) * DD + c0 + i * 64) = v;
        }
      } else {
#pragma unroll
        for (int c = 0; c < 4; ++c) {
          int ch = c * 512 + t, d = ch >> 3, lc = (ch & 7) * 8;
          ushort8 v = *(const ushort8*)&tile[d * 72 + lc];
          *(ushort8*)(VT + ((size_t)(b * DD + d)) * LL + lb + lc) = v;
        }
      }
    }
  }
#undef LOADW
}

// ---------------------------------------------------------------------------
// Kernel 2: flash attention v10.  512 thr = 8 waves = 2 qh x 4 kv-grps.
// Each wave: 32 q-rows x 16 kv/iter -> every K/V fragment feeds 2 q-tiles
// (halves LDS frag traffic vs round-7's 16q/wave; attn was LDS-volume-bound
// at 672KB/CU/128kv).  K/V double-buffered in LDS via global_load_lds
// (pre-swizzled source, linear dest), ONE barrier per 64-kv iter; next
// tile's DMA issued at iter start, drained by the end barrier.
// Registers: O 128 + qf 64 + ~40 misc = ~230 (fits 256 @ 2 waves/SIMD —
// the reg-staging of rounds 2-5 overflowed; GLD16 avoids it).
// PV uses mfma_f32_16x16x16f16 (k=16 == kv-grp tile).
// 4-way online-softmax merge at the end (round-2's refchecked scheme).
// ---------------------------------------------------------------------------
__global__ __launch_bounds__(512, 1) void attn(
    const unsigned short* __restrict__ Qb, const unsigned short* __restrict__ Kb,
    const unsigned short* __restrict__ VT, const int* __restrict__ lens,
    float* __restrict__ out) {
  // [0,65536)        K: [2 buf][4 grp][16 kv][256 d], 16B chunk x at x^(kv&7)
  // [65536,131072)   V: [2 buf][4 grp][256 d][16 kv], 16B pair c at c^((d>>2)&1)
  // [131072,143360)  P: [8 wave][32 q][24 hw]
  __shared__ __attribute__((aligned(16))) unsigned char smem[143360];
  const int t = threadIdx.x;
  const int wave = t >> 6, lane = t & 63, quad = lane >> 4, m16 = lane & 15;
  const int qh = wave >> 2, grp = wave & 3;
  unsigned short* Pw = (unsigned short*)(smem + 131072 + wave * 1536);

  const int b = blockIdx.x;  // batch on x -> XCD L2 affinity
  const int q0 = blockIdx.y * 64 + qh * 32;
  const int len = lens[b];
  const size_t baseQK = (size_t)b * LL * DD;
  const size_t baseVT = (size_t)b * DD * LL;
  const unsigned short* kbase = Kb + baseQK;
  const unsigned short* vbase = VT + baseVT;

  half8 qf[2][8];
#pragma unroll
  for (int mt = 0; mt < 2; ++mt) {
    const unsigned short* qrow =
        Qb + baseQK + (size_t)(q0 + mt * 16 + m16) * DD + quad * 8;
#pragma unroll
    for (int kb = 0; kb < 8; ++kb)
      qf[mt][kb] = __builtin_bit_cast(half8, *(const ushort8*)(qrow + kb * 32));
  }

  floatx4 O[2][16];
#pragma unroll
  for (int mt = 0; mt < 2; ++mt)
#pragma unroll
    for (int i = 0; i < 16; ++i) O[mt][i] = (floatx4){0, 0, 0, 0};
  float mrow[2][4], lrow[2][4];
#pragma unroll
  for (int mt = 0; mt < 2; ++mt)
#pragma unroll
    for (int r = 0; r < 4; ++r) {
      mrow[mt][r] = -1e30f;
      lrow[mt][r] = 0.f;
    }

// Stage 64 kv (4 grps x 16) into buffer BUF.  K: 2048 16B chunks; per grp
// 512 chunks (16 kv x 32); source chunk x pre-swizzled by kv&7.
// V: 2048 chunks; per grp 512 (256 d x 2); source pair c pre-swz (d>>2)&1.
#define STAGE(BUF, KV0)                                                       \
  {                                                                           \
    _Pragma("unroll") for (int c = 0; c < 4; ++c) {                           \
      int i = c * 512 + t;                                                    \
      int g = i >> 9, ci = i & 511, row = ci >> 5, xx = ci & 31;              \
      const unsigned short* src = kbase +                                     \
          (size_t)((KV0) + g * 16 + row) * DD + ((xx ^ (row & 7)) << 3);      \
      GLD16(src, smem + (BUF)*32768 + i * 16);                                \
    }                                                                         \
    _Pragma("unroll") for (int c = 0; c < 4; ++c) {                           \
      int i = c * 512 + t;                                                    \
      int g = i >> 9, ci = i & 511, d = ci >> 1, ch = ci & 1;                 \
      const unsigned short* src = vbase + (size_t)d * LL + (KV0) + g * 16 +   \
                                  ((ch ^ ((d >> 2) & 1)) << 3);               \
      GLD16(src, smem + 65536 + (BUF)*32768 + i * 16);                        \
    }                                                                         \
  }

  const int T = (len + 63) >> 6;  // 64 kv per iter
  STAGE(0, 0);
  __syncthreads();  // drain initial DMA

  for (int it = 0; it < T; ++it) {
    const int cur = it & 1;
    if (it + 1 < T) STAGE(cur ^ 1, (it + 1) * 64);  // hides under compute
    const int kvg = it * 64 + grp * 16;

    if (kvg < len) {
      const unsigned short* Kg =
          (const unsigned short*)(smem + cur * 32768 + grp * 8192);
      const unsigned short* Vg =
          (const unsigned short*)(smem + 65536 + cur * 32768 + grp * 8192);
      // S = Q K^T  (2 q-tiles share each K fragment)
      floatx4 s[2] = {{0, 0, 0, 0}, {0, 0, 0, 0}};
      __builtin_amdgcn_s_setprio(1);
#pragma unroll
      for (int kb = 0; kb < 8; ++kb) {
        half8 kf = __builtin_bit_cast(
            half8, *(const ushort8*)&Kg[m16 * 256 +
                                        (((kb * 4 + quad) ^ (m16 & 7)) << 3)]);
        s[0] = __builtin_amdgcn_mfma_f32_16x16x32_f16(qf[0][kb], kf, s[0], 0, 0, 0);
        s[1] = __builtin_amdgcn_mfma_f32_16x16x32_f16(qf[1][kb], kf, s[1], 0, 0, 0);
      }
      __builtin_amdgcn_s_setprio(0);

      // online softmax: S col(kv)=m16, row(q)=quad*4+r (+mt*16)
      const bool valid = (kvg + m16) < len;
      float al[2][4];
      bool grew = false;
#pragma unroll
      for (int mt = 0; mt < 2; ++mt)
#pragma unroll
        for (int r = 0; r < 4; ++r) {
          float sv = valid ? s[mt][r] * 0.0625f : -1e30f;
          float v = sv;
          v = fmaxf(v, __shfl_xor(v, 1));
          v = fmaxf(v, __shfl_xor(v, 2));
          v = fmaxf(v, __shfl_xor(v, 4));
          v = fmaxf(v, __shfl_xor(v, 8));
          float mo = mrow[mt][r];
          float mn = fmaxf(mo, v);
          grew |= (mn > mo);
          al[mt][r] = __expf(mo - mn);
          mrow[mt][r] = mn;
          float p = __expf(sv - mn);
          Pw[(mt * 16 + quad * 4 + r) * 24 + m16] = f2h(p);
          float sum = p;
          sum += __shfl_xor(sum, 1);
          sum += __shfl_xor(sum, 2);
          sum += __shfl_xor(sum, 4);
          sum += __shfl_xor(sum, 8);
          lrow[mt][r] = lrow[mt][r] * al[mt][r] + sum;
        }
      if (__any(grew)) {  // defer-rescale: skip O-pass when max unchanged
#pragma unroll
        for (int mt = 0; mt < 2; ++mt)
#pragma unroll
          for (int nb = 0; nb < 16; ++nb)
#pragma unroll
            for (int r = 0; r < 4; ++r) O[mt][nb][r] *= al[mt][r];
      }

      // PV: O[32q][256d] += P[32q][16kv] * V[16kv][256d], k=16 MFMA
      half4 pf[2];
#pragma unroll
      for (int mt = 0; mt < 2; ++mt)
        pf[mt] = __builtin_bit_cast(
            half4, *(const unsigned long long*)&Pw[(mt * 16 + m16) * 24 +
                                                   quad * 4]);
      __builtin_amdgcn_s_setprio(1);
#pragma unroll
      for (int nb = 0; nb < 16; ++nb) {
        const int d = nb * 16 + m16;
        const int u = quad ^ (((d >> 2) & 1) << 1);
        half4 vf = __builtin_bit_cast(
            half4, *(const unsigned long long*)&Vg[d * 16 + u * 4]);
        O[0][nb] = __builtin_amdgcn_mfma_f32_16x16x16f16(pf[0], vf, O[0][nb], 0, 0, 0);
        O[1][nb] = __builtin_amdgcn_mfma_f32_16x16x16f16(pf[1], vf, O[1][nb], 0, 0, 0);
      }
      __builtin_amdgcn_s_setprio(0);
    }
    __syncthreads();  // frees cur buffer; drains next-tile DMA
  }
#undef STAGE

  // ---- 4-way merge: (grp2,grp3)->(grp0,grp1), then grp1->grp0 ----
  float* OmB = (float*)smem;               // 4 slots x 32 x 257 f32
  float* mlB = (float*)(smem + 131584);    // 4 slots x 32 x {m,l}
  __syncthreads();
  if (grp >= 2) {
    const int slot = (grp & 1) + 2 * qh;
    float* Om = OmB + slot * 8224;
    float* ml = mlB + slot * 64;
#pragma unroll
    for (int mt = 0; mt < 2; ++mt)
#pragma unroll
      for (int nb = 0; nb < 16; ++nb)
#pragma unroll
        for (int r = 0; r < 4; ++r)
          Om[(mt * 16 + quad * 4 + r) * 257 + nb * 16 + m16] = O[mt][nb][r];
    if (m16 == 0)
#pragma unroll
      for (int mt = 0; mt < 2; ++mt)
#pragma unroll
        for (int r = 0; r < 4; ++r) {
          ml[(mt * 16 + quad * 4 + r) * 2] = mrow[mt][r];
          ml[(mt * 16 + quad * 4 + r) * 2 + 1] = lrow[mt][r];
        }
  }
  __syncthreads();
  if (grp < 2) {
    const int slot = grp + 2 * qh;
    float* Om = OmB + slot * 8224;
    float* ml = mlB + slot * 64;
    float av[2][4], bv[2][4];
#pragma unroll
    for (int mt = 0; mt < 2; ++mt)
#pragma unroll
      for (int r = 0; r < 4; ++r) {
        const int row = mt * 16 + quad * 4 + r;
        float mB = ml[row * 2], lB = ml[row * 2 + 1];
        float m = fmaxf(mrow[mt][r], mB);
        float a = __expf(mrow[mt][r] - m);
        float bb = __expf(mB - m);
        lrow[mt][r] = lrow[mt][r] * a + lB * bb;
        mrow[mt][r] = m;
        av[mt][r] = a;
        bv[mt][r] = bb;
      }
#pragma unroll
    for (int mt = 0; mt < 2; ++mt)
#pragma unroll
      for (int nb = 0; nb < 16; ++nb)
#pragma unroll
        for (int r = 0; r < 4; ++r)
          O[mt][nb][r] =
              O[mt][nb][r] * av[mt][r] +
              Om[(mt * 16 + quad * 4 + r) * 257 + nb * 16 + m16] * bv[mt][r];
  }
  __syncthreads();
  if (grp == 1) {
    const int slot = qh;
    float* Om = OmB + slot * 8224;
    float* ml = mlB + slot * 64;
#pragma unroll
    for (int mt = 0; mt < 2; ++mt)
#pragma unroll
      for (int nb = 0; nb < 16; ++nb)
#pragma unroll
        for (int r = 0; r < 4; ++r)
          Om[(mt * 16 + quad * 4 + r) * 257 + nb * 16 + m16] = O[mt][nb][r];
    if (m16 == 0)
#pragma unroll
      for (int mt = 0; mt < 2; ++mt)
#pragma unroll
        for (int r = 0; r < 4; ++r) {
          ml[(mt * 16 + quad * 4 + r) * 2] = mrow[mt][r];
          ml[(mt * 16 + quad * 4 + r) * 2 + 1] = lrow[mt][r];
        }
  }
  __syncthreads();
  if (grp == 0) {
    const int slot = qh;
    float* Om = OmB + slot * 8224;
    float* ml = mlB + slot * 64;
    float av[2][4], bv[2][4], inv[2][4];
#pragma unroll
    for (int mt = 0; mt < 2; ++mt)
#pragma unroll
      for (int r = 0; r < 4; ++r) {
        const int row = mt * 16 + quad * 4 + r;
        float mB = ml[row * 2], lB = ml[row * 2 + 1];
        float m = fmaxf(mrow[mt][r], mB);
        float a = __expf(mrow[mt][r] - m);
        float bb = __expf(mB - m);
        av[mt][r] = a;
        bv[mt][r] = bb;
        inv[mt][r] = 1.f / (lrow[mt][r] * a + lB * bb);
      }
#pragma unroll
    for (int mt = 0; mt < 2; ++mt)
#pragma unroll
      for (int nb = 0; nb < 16; ++nb)
#pragma unroll
        for (int r = 0; r < 4; ++r) {
          float ob = Om[(mt * 16 + quad * 4 + r) * 257 + nb * 16 + m16];
          out[baseQK + (size_t)(q0 + mt * 16 + quad * 4 + r) * DD + nb * 16 +
              m16] = (O[mt][nb][r] * av[mt][r] + ob * bv[mt][r]) * inv[mt][r];
        }
  }
}

extern "C" void kernel_launch(void* const* d_in, const int* in_sizes, int n_in,
                              void* d_out, int out_size, void* d_ws, size_t ws_size,
                              hipStream_t stream) {
  const float* x = (const float*)d_in[0];
  const float* Wq = (const float*)d_in[1];
  const float* Wk = (const float*)d_in[2];
  const float* Wv = (const float*)d_in[3];
  const int* lens = (const int*)d_in[4];
  unsigned short* Qb = (unsigned short*)d_ws;
  unsigned short* Kb = Qb + (size_t)BB * LL * DD;
  unsigned short* VT = Kb + (size_t)BB * LL * DD;
  float* out = (float*)d_out;

  proj<<<256, 512, 0, stream>>>(x, Wq, Wk, Wv, Qb, Kb, VT);
  attn<<<dim3(8, 32), 512, 0, stream>>>(Qb, Kb, VT, lens, out);
}

// Round 11
// 182.728 us; speedup vs baseline: 1.4662x; 1.4662x over previous
//
#include <hip/hip_runtime.h>

#define BB 8
#define LL 2048
#define DD 256

typedef _Float16 half8 __attribute__((ext_vector_type(8)));
typedef float floatx4 __attribute__((ext_vector_type(4)));
typedef unsigned short ushort8 __attribute__((ext_vector_type(8)));

__device__ inline unsigned short f2h(float f) {
  _Float16 h = (_Float16)f;
  return __builtin_bit_cast(unsigned short, h);
}

#define GLD16(src, ldsbase)                                                    \
  __builtin_amdgcn_global_load_lds(                                           \
      (const __attribute__((address_space(1))) unsigned int*)(src),           \
      (__attribute__((address_space(3))) unsigned int*)(ldsbase), 16, 0, 0)

// ---------------------------------------------------------------------------
// Kernel 1: fused W-convert + QKV projection (unchanged; ~10-15us).
// ---------------------------------------------------------------------------
__global__ __launch_bounds__(512) void proj(
    const float* __restrict__ x, const float* __restrict__ Wq,
    const float* __restrict__ Wk, const float* __restrict__ Wv,
    unsigned short* __restrict__ Qb, unsigned short* __restrict__ Kb,
    unsigned short* __restrict__ VT) {
  __shared__ __attribute__((aligned(16))) unsigned char smem[69632];
  unsigned short* Ws = (unsigned short*)smem;
  unsigned short* tile = (unsigned short*)(smem + 32768);
  const int t = threadIdx.x;
  const int wave = t >> 6, lane = t & 63, quad = lane >> 4, m16 = lane & 15;
  const int ot = wave >> 1, p = wave & 1;
  const int l0g = blockIdx.x * 64;
  const int b = l0g >> 11, lb = l0g & 2047;

  half8 xf[2][8];
#pragma unroll
  for (int j = 0; j < 2; ++j) {
    const float* xp =
        x + (size_t)(l0g + (p * 2 + j) * 16 + m16) * DD + quad * 8;
#pragma unroll
    for (int kb = 0; kb < 8; ++kb) {
      float4 a = *(const float4*)(xp + kb * 32);
      float4 c = *(const float4*)(xp + kb * 32 + 4);
      ushort8 u = {f2h(a.x), f2h(a.y), f2h(a.z), f2h(a.w),
                   f2h(c.x), f2h(c.y), f2h(c.z), f2h(c.w)};
      xf[j][kb] = __builtin_bit_cast(half8, u);
    }
  }

  float4 wA[4], wB[4];
#define LOADW(G)                                                              \
  {                                                                           \
    const int mat_ = (G) >> 2, og_ = (G)&3;                                   \
    const float* Wm = (mat_ == 0) ? Wq : (mat_ == 1) ? Wk : Wv;               \
    _Pragma("unroll") for (int c = 0; c < 4; ++c) {                           \
      int ch = c * 512 + t, row = ch >> 5, cc = ch & 31;                      \
      const float* s = Wm + (size_t)(og_ * 64 + row) * DD + cc * 8;           \
      wA[c] = *(const float4*)s;                                              \
      wB[c] = *(const float4*)(s + 4);                                        \
    }                                                                         \
  }

  LOADW(0);
  asm volatile("" ::: "memory");

  for (int g = 0; g < 12; ++g) {
    const int mat = g >> 2, og = g & 3;
    __syncthreads();
#pragma unroll
    for (int c = 0; c < 4; ++c) {
      int ch = c * 512 + t, row = ch >> 5, cc = ch & 31;
      ushort8 u = {f2h(wA[c].x), f2h(wA[c].y), f2h(wA[c].z), f2h(wA[c].w),
                   f2h(wB[c].x), f2h(wB[c].y), f2h(wB[c].z), f2h(wB[c].w)};
      *(ushort8*)&Ws[row * 256 + ((cc ^ (row & 7)) << 3)] = u;
    }
    __syncthreads();
    if (g < 11) {
      LOADW(g + 1);
      asm volatile("" ::: "memory");
    }

    floatx4 acc[2] = {{0, 0, 0, 0}, {0, 0, 0, 0}};
    if (mat < 2) {
#pragma unroll
      for (int kb = 0; kb < 8; ++kb) {
        half8 wf = __builtin_bit_cast(
            half8, *(const ushort8*)&Ws[(ot * 16 + m16) * 256 +
                                        (((kb * 4 + quad) ^ (m16 & 7)) << 3)]);
        acc[0] = __builtin_amdgcn_mfma_f32_16x16x32_f16(xf[0][kb], wf,
                                                        acc[0], 0, 0, 0);
        acc[1] = __builtin_amdgcn_mfma_f32_16x16x32_f16(xf[1][kb], wf,
                                                        acc[1], 0, 0, 0);
      }
#pragma unroll
      for (int j = 0; j < 2; ++j)
#pragma unroll
        for (int r = 0; r < 4; ++r)
          tile[((p * 2 + j) * 16 + quad * 4 + r) * 264 + og * 64 + ot * 16 +
               m16] = f2h(acc[j][r]);
    } else {
#pragma unroll
      for (int kb = 0; kb < 8; ++kb) {
        half8 wf = __builtin_bit_cast(
            half8, *(const ushort8*)&Ws[(ot * 16 + m16) * 256 +
                                        (((kb * 4 + quad) ^ (m16 & 7)) << 3)]);
        acc[0] = __builtin_amdgcn_mfma_f32_16x16x32_f16(wf, xf[0][kb],
                                                        acc[0], 0, 0, 0);
        acc[1] = __builtin_amdgcn_mfma_f32_16x16x32_f16(wf, xf[1][kb],
                                                        acc[1], 0, 0, 0);
      }
#pragma unroll
      for (int j = 0; j < 2; ++j)
#pragma unroll
        for (int r = 0; r < 4; ++r)
          tile[(og * 64 + ot * 16 + quad * 4 + r) * 72 + (p * 2 + j) * 16 +
               m16] = f2h(acc[j][r]);
    }

    if (og == 3) {
      __syncthreads();
      if (mat < 2) {
        unsigned short* Out = mat ? Kb : Qb;
        const int row = t >> 3, c0 = (t & 7) * 8;
#pragma unroll
        for (int i = 0; i < 4; ++i) {
          ushort8 v = *(const ushort8*)&tile[row * 264 + c0 + i * 64];
          *(ushort8*)(Out + (size_t)(l0g + row) * DD + c0 + i * 64) = v;
        }
      } else {
#pragma unroll
        for (int c = 0; c < 4; ++c) {
          int ch = c * 512 + t, d = ch >> 3, lc = (ch & 7) * 8;
          ushort8 v = *(const ushort8*)&tile[d * 72 + lc];
          *(ushort8*)(VT + ((size_t)(b * DD + d)) * LL + lb + lc) = v;
        }
      }
    }
  }
#undef LOADW
}

// ---------------------------------------------------------------------------
// Kernel 2: flash attention v11 = round-7 per-wave geometry (16 q/wave,
// 2 kv-groups x 4 q-waves — the register profile that works) + v10's DMA
// staging (global_load_lds, double-buffered LDS, ONE barrier per iter).
// Removes 128KB/iter of ds_write instruction traffic and the
// staging-latency exposure (DMA for tile t+1 issued at start of iter t,
// drained by its end barrier).  64 kv per iter (grp g: kv it*64+g*32).
// V swizzle c^((d^(d>>2))&3): 2-way max on the 16-row PV read window.
// Defer-rescale skips the O-mul pass when no row max grew (T13).
// ---------------------------------------------------------------------------
__global__ __launch_bounds__(512, 1) void attn(
    const unsigned short* __restrict__ Qb, const unsigned short* __restrict__ Kb,
    const unsigned short* __restrict__ VT, const int* __restrict__ lens,
    float* __restrict__ out) {
  // [0,65536)        K: [2 buf][2 grp][32 kv][256 d hw], chunk c at c^(kv&7)
  // [65536,131072)   V: [2 buf][2 grp][256 d][32 kv hw], chunk c at c^vs(d)
  // [131072,141312)  P: [8 wave][16 q][40 hw]
  __shared__ __attribute__((aligned(16))) unsigned char smem[141312];
  const int t = threadIdx.x;
  const int wave = t >> 6, lane = t & 63, quad = lane >> 4, m16 = lane & 15;
  const int grp = wave >> 2, qw = wave & 3;
  unsigned short* Pw = (unsigned short*)(smem + 131072 + wave * 1280);

  const int b = blockIdx.x;  // batch on x -> XCD L2 affinity
  const int q0 = blockIdx.y * 64;
  const int len = lens[b];
  const size_t baseQK = (size_t)b * LL * DD;
  const size_t baseVT = (size_t)b * DD * LL;
  const unsigned short* kbase = Kb + baseQK;
  const unsigned short* vbase = VT + baseVT;

  half8 qf[8];
  {
    const unsigned short* qrow =
        Qb + baseQK + (size_t)(q0 + qw * 16 + m16) * DD + quad * 8;
#pragma unroll
    for (int kb = 0; kb < 8; ++kb)
      qf[kb] = __builtin_bit_cast(half8, *(const ushort8*)(qrow + kb * 32));
  }

  floatx4 O[16];
#pragma unroll
  for (int i = 0; i < 16; ++i) O[i] = (floatx4){0, 0, 0, 0};
  float mrow[4] = {-1e30f, -1e30f, -1e30f, -1e30f};
  float lrow[4] = {0.f, 0.f, 0.f, 0.f};

#define VSWZ(d) (((d) ^ ((d) >> 2)) & 3)
// Stage 64 kv into buffer BUF.  K: 2048 chunks (grp g = i>>10, 32 rows x 32
// chunks); V: 2048 chunks (256 d x 4 chunks per grp).  LDS dest linear in i;
// global source pre-swizzled so the swizzled read finds its data.
#define STAGE(BUF, KV0)                                                       \
  {                                                                           \
    _Pragma("unroll") for (int c = 0; c < 4; ++c) {                           \
      int i = c * 512 + t;                                                    \
      int g = i >> 10, ci = i & 1023, row = ci >> 5, pp = ci & 31;            \
      const unsigned short* src = kbase +                                     \
          (size_t)((KV0) + g * 32 + row) * DD + ((pp ^ (row & 7)) << 3);      \
      GLD16(src, smem + (BUF)*32768 + i * 16);                                \
    }                                                                         \
    _Pragma("unroll") for (int c = 0; c < 4; ++c) {                           \
      int i = c * 512 + t;                                                    \
      int g = i >> 10, ci = i & 1023, d = ci >> 2, pp = ci & 3;               \
      const unsigned short* src = vbase + (size_t)d * LL + (KV0) + g * 32 +   \
                                  ((pp ^ VSWZ(d)) << 3);                      \
      GLD16(src, smem + 65536 + (BUF)*32768 + i * 16);                        \
    }                                                                         \
  }

  const int T = (len + 63) >> 6;  // 64 kv per iter
  STAGE(0, 0);
  __syncthreads();  // drain initial DMA

  for (int it = 0; it < T; ++it) {
    const int cur = it & 1;
    if (it + 1 < T) {
      STAGE(cur ^ 1, (it + 1) * 64);  // hides under this iter's compute
      asm volatile("" ::: "memory");  // pin issue point
    }
    const int kvg = it * 64 + grp * 32;

    if (kvg < len) {
      const unsigned short* Kg =
          (const unsigned short*)(smem + cur * 32768 + grp * 16384);
      const unsigned short* Vg =
          (const unsigned short*)(smem + 65536 + cur * 32768 + grp * 16384);

      // S = Q K^T : S[16q][32kv], n in {0,1}
      floatx4 s[2] = {{0, 0, 0, 0}, {0, 0, 0, 0}};
      __builtin_amdgcn_s_setprio(1);
#pragma unroll
      for (int kb = 0; kb < 8; ++kb) {
#pragma unroll
        for (int n = 0; n < 2; ++n) {
          half8 kf = __builtin_bit_cast(
              half8, *(const ushort8*)&Kg[(n * 16 + m16) * 256 +
                                          (((kb * 4 + quad) ^ (m16 & 7)) << 3)]);
          s[n] = __builtin_amdgcn_mfma_f32_16x16x32_f16(qf[kb], kf, s[n], 0, 0, 0);
        }
      }
      __builtin_amdgcn_s_setprio(0);

      float sv[2][4];
      bool vld[2];
#pragma unroll
      for (int n = 0; n < 2; ++n) vld[n] = (kvg + n * 16 + m16) < len;
#pragma unroll
      for (int n = 0; n < 2; ++n)
#pragma unroll
        for (int r = 0; r < 4; ++r)
          sv[n][r] = vld[n] ? s[n][r] * 0.0625f : -1e30f;

      float al[4];
      bool grew = false;
#pragma unroll
      for (int r = 0; r < 4; ++r) {
        float v = fmaxf(sv[0][r], sv[1][r]);
        v = fmaxf(v, __shfl_xor(v, 1));
        v = fmaxf(v, __shfl_xor(v, 2));
        v = fmaxf(v, __shfl_xor(v, 4));
        v = fmaxf(v, __shfl_xor(v, 8));
        float mo = mrow[r];
        float mn = fmaxf(mo, v);
        grew |= (mn > mo);
        al[r] = __expf(mo - mn);
        mrow[r] = mn;
        float sum = 0.f;
#pragma unroll
        for (int n = 0; n < 2; ++n) {
          float p = __expf(sv[n][r] - mn);
          Pw[(quad * 4 + r) * 40 + n * 16 + m16] = f2h(p);
          sum += p;
        }
        sum += __shfl_xor(sum, 1);
        sum += __shfl_xor(sum, 2);
        sum += __shfl_xor(sum, 4);
        sum += __shfl_xor(sum, 8);
        lrow[r] = lrow[r] * al[r] + sum;
      }
      if (__any(grew)) {  // defer-rescale: al==1 everywhere when !grew
#pragma unroll
        for (int i = 0; i < 16; ++i)
#pragma unroll
          for (int r = 0; r < 4; ++r) O[i][r] *= al[r];
      }

      // PV: O[16q][256d] += P[16q][32kv] V[32kv][256d]  (k=32)
      half8 pf = __builtin_bit_cast(half8,
                                    *(const ushort8*)&Pw[m16 * 40 + quad * 8]);
      __builtin_amdgcn_s_setprio(1);
#pragma unroll
      for (int nb = 0; nb < 16; ++nb) {
        const int d = nb * 16 + m16;
        half8 vf = __builtin_bit_cast(
            half8, *(const ushort8*)&Vg[d * 32 + ((quad ^ VSWZ(d)) << 3)]);
        O[nb] = __builtin_amdgcn_mfma_f32_16x16x32_f16(pf, vf, O[nb], 0, 0, 0);
      }
      __builtin_amdgcn_s_setprio(0);
    }
    __syncthreads();  // next buf's DMA drained; cur released for restage
  }
#undef STAGE
#undef VSWZ

  // ---- merge group 1 into group 0 via LDS (aliases K/V region) ----
  __syncthreads();
  float* Om = (float*)(smem) + qw * 4112;       // 16 rows x 257 f32 per wave
  float* ml = (float*)(smem + 65792) + qw * 32; // [2][16] per wave
  if (grp == 1) {
#pragma unroll
    for (int nb = 0; nb < 16; ++nb)
#pragma unroll
      for (int r = 0; r < 4; ++r)
        Om[(quad * 4 + r) * 257 + nb * 16 + m16] = O[nb][r];
    if (m16 == 0)
#pragma unroll
      for (int r = 0; r < 4; ++r) {
        ml[(quad * 4 + r) * 2] = mrow[r];
        ml[(quad * 4 + r) * 2 + 1] = lrow[r];
      }
  }
  __syncthreads();
  if (grp == 0) {
    float a[4], bf[4], inv[4];
#pragma unroll
    for (int r = 0; r < 4; ++r) {
      float mB = ml[(quad * 4 + r) * 2];
      float lB = ml[(quad * 4 + r) * 2 + 1];
      float m = fmaxf(mrow[r], mB);
      a[r] = __expf(mrow[r] - m);
      bf[r] = __expf(mB - m);
      inv[r] = 1.f / (lrow[r] * a[r] + lB * bf[r]);
    }
#pragma unroll
    for (int nb = 0; nb < 16; ++nb)
#pragma unroll
      for (int r = 0; r < 4; ++r) {
        float ob = Om[(quad * 4 + r) * 257 + nb * 16 + m16];
        out[baseQK + (size_t)(q0 + qw * 16 + quad * 4 + r) * DD + nb * 16 +
            m16] = (O[nb][r] * a[r] + ob * bf[r]) * inv[r];
      }
  }
}

extern "C" void kernel_launch(void* const* d_in, const int* in_sizes, int n_in,
                              void* d_out, int out_size, void* d_ws, size_t ws_size,
                              hipStream_t stream) {
  const float* x = (const float*)d_in[0];
  const float* Wq = (const float*)d_in[1];
  const float* Wk = (const float*)d_in[2];
  const float* Wv = (const float*)d_in[3];
  const int* lens = (const int*)d_in[4];
  unsigned short* Qb = (unsigned short*)d_ws;
  unsigned short* Kb = Qb + (size_t)BB * LL * DD;
  unsigned short* VT = Kb + (size_t)BB * LL * DD;
  float* out = (float*)d_out;

  proj<<<256, 512, 0, stream>>>(x, Wq, Wk, Wv, Qb, Kb, VT);
  attn<<<dim3(8, 32), 512, 0, stream>>>(Qb, Kb, VT, lens, out);
}

// Round 12
// 167.188 us; speedup vs baseline: 1.6024x; 1.0930x over previous
//
#include <hip/hip_runtime.h>

#define BB 8
#define LL 2048
#define DD 256

typedef _Float16 half8 __attribute__((ext_vector_type(8)));
typedef float floatx4 __attribute__((ext_vector_type(4)));
typedef unsigned short ushort8 __attribute__((ext_vector_type(8)));

__device__ inline unsigned short f2h(float f) {
  _Float16 h = (_Float16)f;
  return __builtin_bit_cast(unsigned short, h);
}

#define GLD16(src, ldsbase)                                                    \
  __builtin_amdgcn_global_load_lds(                                           \
      (const __attribute__((address_space(1))) unsigned int*)(src),           \
      (__attribute__((address_space(3))) unsigned int*)(ldsbase), 16, 0, 0)

// ---------------------------------------------------------------------------
// Kernel 0: W fp32 -> fp16, Wh[3][256][256].  grid 96, block 256.
// Wq additionally scaled by 1/sqrt(d)=0.0625 (exact in fp16) so attn's
// softmax input needs no per-element scale.
// ---------------------------------------------------------------------------
__global__ __launch_bounds__(256) void wcvt(
    const float* __restrict__ Wq, const float* __restrict__ Wk,
    const float* __restrict__ Wv, unsigned short* __restrict__ Wh) {
  const int bm = blockIdx.x >> 5;
  const float* src = (bm == 0) ? Wq : (bm == 1) ? Wk : Wv;
  const float sc = (bm == 0) ? 0.0625f : 1.0f;
  const int off = (blockIdx.x & 31) * 2048 + threadIdx.x * 8;
  float4 a = *(const float4*)(src + off);
  float4 b = *(const float4*)(src + off + 4);
  ushort8 u = {f2h(a.x * sc), f2h(a.y * sc), f2h(a.z * sc), f2h(a.w * sc),
               f2h(b.x * sc), f2h(b.y * sc), f2h(b.z * sc), f2h(b.w * sc)};
  *(ushort8*)(Wh + bm * 65536 + off) = u;
}

// ---------------------------------------------------------------------------
// Kernel 1: fused QKV projection (round-6 v2, best measured).
// W staged per 64-row group through LDS via global_load_lds (linear 1KB
// per instr, source chunks pre-swizzled cc^(row&7)), fragments read from
// LDS (<=2-way).  LDS 52KB -> 3 blocks/CU.
// ---------------------------------------------------------------------------
__global__ __launch_bounds__(256) void proj(
    const float* __restrict__ x, const unsigned short* __restrict__ Wh,
    unsigned short* __restrict__ Qb, unsigned short* __restrict__ Kb,
    unsigned short* __restrict__ VT) {
  __shared__ __attribute__((aligned(16))) unsigned char smem[53248];
  unsigned short* Ws = (unsigned short*)smem;
  unsigned short* tile = (unsigned short*)(smem + 32768);
  const int t = threadIdx.x;
  const int wave = t >> 6, lane = t & 63, quad = lane >> 4, m16 = lane & 15;
  const int l0g = blockIdx.x * 32;
  const int b = l0g >> 11, lb = l0g & 2047;

  half8 xf[2][8];
#pragma unroll
  for (int mt = 0; mt < 2; ++mt) {
    const float* xp = x + (size_t)(l0g + mt * 16 + m16) * DD + quad * 8;
#pragma unroll
    for (int kb = 0; kb < 8; ++kb) {
      float4 a = *(const float4*)(xp + kb * 32);
      float4 c = *(const float4*)(xp + kb * 32 + 4);
      ushort8 u = {f2h(a.x), f2h(a.y), f2h(a.z), f2h(a.w),
                   f2h(c.x), f2h(c.y), f2h(c.z), f2h(c.w)};
      xf[mt][kb] = __builtin_bit_cast(half8, u);
    }
  }

  for (int gg = 0; gg < 12; ++gg) {
    const int mat = gg >> 2, og = gg & 3;
#pragma unroll
    for (int c = 0; c < 8; ++c) {
      int ch = c * 256 + t;
      int row = ch >> 5, cc = ch & 31;
      const unsigned short* src = Wh + mat * 65536 +
          (size_t)(og * 64 + row) * DD + ((cc ^ (row & 7)) << 3);
      GLD16(src, smem + (c * 256 + wave * 64) * 16);
    }
    __syncthreads();  // drain DMA

    const int ot = og * 4 + wave;
    const int wrow = wave * 16 + m16;
    floatx4 acc[2] = {{0, 0, 0, 0}, {0, 0, 0, 0}};
    if (mat < 2) {
#pragma unroll
      for (int kb = 0; kb < 8; ++kb) {
        half8 wf = __builtin_bit_cast(
            half8, *(const ushort8*)&Ws[wrow * 256 +
                                        (((kb * 4 + quad) ^ (wrow & 7)) << 3)]);
        acc[0] = __builtin_amdgcn_mfma_f32_16x16x32_f16(xf[0][kb], wf,
                                                        acc[0], 0, 0, 0);
        acc[1] = __builtin_amdgcn_mfma_f32_16x16x32_f16(xf[1][kb], wf,
                                                        acc[1], 0, 0, 0);
      }
#pragma unroll
      for (int mt = 0; mt < 2; ++mt)
#pragma unroll
        for (int r = 0; r < 4; ++r)
          tile[(mt * 16 + quad * 4 + r) * 264 + ot * 16 + m16] =
              f2h(acc[mt][r]);
    } else {
#pragma unroll
      for (int kb = 0; kb < 8; ++kb) {
        half8 wf = __builtin_bit_cast(
            half8, *(const ushort8*)&Ws[wrow * 256 +
                                        (((kb * 4 + quad) ^ (wrow & 7)) << 3)]);
        acc[0] = __builtin_amdgcn_mfma_f32_16x16x32_f16(wf, xf[0][kb],
                                                        acc[0], 0, 0, 0);
        acc[1] = __builtin_amdgcn_mfma_f32_16x16x32_f16(wf, xf[1][kb],
                                                        acc[1], 0, 0, 0);
      }
#pragma unroll
      for (int mt = 0; mt < 2; ++mt)
#pragma unroll
        for (int r = 0; r < 4; ++r)
          tile[(ot * 16 + quad * 4 + r) * 40 + mt * 16 + m16] =
              f2h(acc[mt][r]);
    }
    __syncthreads();

    if (og == 3) {
      if (mat < 2) {
        unsigned short* Out = mat ? Kb : Qb;
        const int row = t >> 3, c0 = (t & 7) * 8;
#pragma unroll
        for (int i = 0; i < 4; ++i) {
          ushort8 v = *(const ushort8*)&tile[row * 264 + c0 + i * 64];
          *(ushort8*)(Out + (size_t)(l0g + row) * DD + c0 + i * 64) = v;
        }
      } else {
        const int dd = t >> 2, lc = (t & 3) * 8;
#pragma unroll
        for (int p = 0; p < 4; ++p) {
          const int d = p * 64 + dd;
          ushort8 v = *(const ushort8*)&tile[d * 40 + lc];
          *(ushort8*)(VT + ((size_t)(b * DD + d)) * LL + lb + lc) = v;
        }
      }
      __syncthreads();
    }
  }
}

// ---------------------------------------------------------------------------
// Kernel 2: flash attention (round-6 structure, best measured 84us;
// LDS-throughput-bound ~672KB/CU/iter).  Two local tweaks:
//   - Q pre-scaled by 1/sqrt(d) in wcvt -> no per-element scale here.
//   - defer-rescale (T13): skip the 64-fmul O-pass when no row max grew
//     (al == 1.0 exactly then).
// ---------------------------------------------------------------------------
__global__ __launch_bounds__(512, 2) void attn(
    const unsigned short* __restrict__ Qb, const unsigned short* __restrict__ Kb,
    const unsigned short* __restrict__ VT, const int* __restrict__ lens,
    float* __restrict__ out) {
  // [0,65536): Ks (2 grp x 64x256)  [65536,131072): Vs (2 grp x 256x64)
  // [131072,149504): Ps (8 waves x 16x72)
  __shared__ __attribute__((aligned(16))) unsigned char smem[149504];
  const int t = threadIdx.x;
  const int wave = t >> 6, lane = t & 63, quad = lane >> 4, m16 = lane & 15;
  const int grp = wave >> 2, qw = wave & 3, tgl = t & 255;
  unsigned short* Ks = (unsigned short*)(smem + grp * 32768);
  unsigned short* Vs = (unsigned short*)(smem + 65536 + grp * 32768);
  unsigned short* Pw = (unsigned short*)(smem + 131072 + wave * 2304);

  const int b = blockIdx.x;           // batch on x -> XCD affinity
  const int q0 = blockIdx.y * 64;
  const int len = lens[b];
  const size_t baseQK = (size_t)b * LL * DD;
  const size_t baseVT = (size_t)b * DD * LL;

  half8 qf[8];
  {
    const unsigned short* qrow =
        Qb + baseQK + (size_t)(q0 + qw * 16 + m16) * DD + quad * 8;
    for (int kb = 0; kb < 8; ++kb)
      qf[kb] = __builtin_bit_cast(half8, *(const ushort8*)(qrow + kb * 32));
  }

  floatx4 O[16];
  for (int i = 0; i < 16; ++i) O[i] = (floatx4){0, 0, 0, 0};
  float mrow[4] = {-1e30f, -1e30f, -1e30f, -1e30f};
  float lrow[4] = {0.f, 0.f, 0.f, 0.f};

  ushort8 kreg[8], vreg[8];
  const unsigned short* kbase = Kb + baseQK;
  const unsigned short* vbase = VT + baseVT;

#define LOAD_TILES(KV0)                                                      \
  {                                                                          \
    const unsigned short* kp = kbase + (size_t)(KV0)*DD;                     \
    for (int c = 0; c < 8; ++c)                                              \
      kreg[c] = *(const ushort8*)(kp + (tgl + c * 256) * 8);                 \
    for (int c = 0; c < 8; ++c) {                                            \
      int ch = tgl + c * 256;                                                \
      vreg[c] = *(const ushort8*)(vbase + (size_t)(ch >> 3) * LL + (KV0) +   \
                                  (ch & 7) * 8);                             \
    }                                                                        \
  }

  const int T = (len + 127) >> 7;  // uniform trip count, 128 kv per iter
  LOAD_TILES(grp * 64);
  asm volatile("" ::: "memory");  // pin prefetch issue point

  for (int it = 0; it < T; ++it) {
    const int kv0 = it * 128 + grp * 64;
    __syncthreads();
    for (int c = 0; c < 8; ++c) {
      int ch = tgl + c * 256, row = ch >> 5, cc = ch & 31;
      *(ushort8*)&Ks[row * 256 + (cc ^ (row & 7)) * 8] = kreg[c];
    }
    for (int c = 0; c < 8; ++c) {
      int ch = tgl + c * 256, d = ch >> 3, cc = ch & 7;
      *(ushort8*)&Vs[d * 64 + (cc ^ (d & 7)) * 8] = vreg[c];
    }
    __syncthreads();
    if (it + 1 < T) {
      LOAD_TILES(kv0 + 128);
      asm volatile("" ::: "memory");  // keep loads issued here, results live
    }

    if (kv0 < len) {
      // S = Q K^T (Q pre-scaled by 1/sqrt(d))
      floatx4 s[4];
      for (int n = 0; n < 4; ++n) s[n] = (floatx4){0, 0, 0, 0};
      __builtin_amdgcn_s_setprio(1);
      for (int kb = 0; kb < 8; ++kb)
        for (int n = 0; n < 4; ++n) {
          half8 kf = __builtin_bit_cast(
              half8, *(const ushort8*)&Ks[(n * 16 + m16) * 256 +
                                          (((kb * 4 + quad) ^ (m16 & 7)) * 8)]);
          s[n] = __builtin_amdgcn_mfma_f32_16x16x32_f16(qf[kb], kf, s[n], 0, 0, 0);
        }
      __builtin_amdgcn_s_setprio(0);
      float sv[4][4];
      for (int n = 0; n < 4; ++n) {
        bool valid = (kv0 + n * 16 + m16) < len;
        for (int r = 0; r < 4; ++r)
          sv[n][r] = valid ? s[n][r] : -1e30f;
      }
      float al[4];
      bool grew = false;
      for (int r = 0; r < 4; ++r) {
        float v = fmaxf(fmaxf(sv[0][r], sv[1][r]), fmaxf(sv[2][r], sv[3][r]));
        v = fmaxf(v, __shfl_xor(v, 1));
        v = fmaxf(v, __shfl_xor(v, 2));
        v = fmaxf(v, __shfl_xor(v, 4));
        v = fmaxf(v, __shfl_xor(v, 8));
        float mo = mrow[r];
        float mn = fmaxf(mo, v);
        grew |= (mn > mo);
        al[r] = __expf(mo - mn);
        mrow[r] = mn;
        float sum = 0.f;
        for (int n = 0; n < 4; ++n) {
          float p = __expf(sv[n][r] - mn);
          Pw[(quad * 4 + r) * 72 + n * 16 + m16] = f2h(p);
          sum += p;
        }
        sum += __shfl_xor(sum, 1);
        sum += __shfl_xor(sum, 2);
        sum += __shfl_xor(sum, 4);
        sum += __shfl_xor(sum, 8);
        lrow[r] = lrow[r] * al[r] + sum;
      }
      if (__any(grew)) {  // defer-rescale: al==1 exactly when !grew
        for (int i = 0; i < 16; ++i)
          for (int r = 0; r < 4; ++r) O[i][r] *= al[r];
      }
      half8 pf0 = __builtin_bit_cast(half8,
                                     *(const ushort8*)&Pw[m16 * 72 + quad * 8]);
      half8 pf1 = __builtin_bit_cast(
          half8, *(const ushort8*)&Pw[m16 * 72 + 32 + quad * 8]);
      __builtin_amdgcn_s_setprio(1);
      for (int nb = 0; nb < 16; ++nb) {
        half8 vf0 = __builtin_bit_cast(
            half8, *(const ushort8*)&Vs[(nb * 16 + m16) * 64 +
                                        ((quad ^ (m16 & 7)) * 8)]);
        O[nb] = __builtin_amdgcn_mfma_f32_16x16x32_f16(pf0, vf0, O[nb], 0, 0, 0);
        half8 vf1 = __builtin_bit_cast(
            half8, *(const ushort8*)&Vs[(nb * 16 + m16) * 64 +
                                        (((4 + quad) ^ (m16 & 7)) * 8)]);
        O[nb] = __builtin_amdgcn_mfma_f32_16x16x32_f16(pf1, vf1, O[nb], 0, 0, 0);
      }
      __builtin_amdgcn_s_setprio(0);
    }
  }
#undef LOAD_TILES

  // ---- merge group 1 into group 0 via LDS (aliases Ks/Vs region) ----
  __syncthreads();
  float* Om = (float*)(smem) + qw * 4112;       // 16 rows x 257 f32 per wave
  float* ml = (float*)(smem + 65792) + qw * 32; // [2][16] per wave
  if (grp == 1) {
    for (int nb = 0; nb < 16; ++nb)
      for (int r = 0; r < 4; ++r)
        Om[(quad * 4 + r) * 257 + nb * 16 + m16] = O[nb][r];
    if (m16 == 0)
      for (int r = 0; r < 4; ++r) {
        ml[(quad * 4 + r) * 2] = mrow[r];
        ml[(quad * 4 + r) * 2 + 1] = lrow[r];
      }
  }
  __syncthreads();
  if (grp == 0) {
    float a[4], bf[4], inv[4];
    for (int r = 0; r < 4; ++r) {
      float mB = ml[(quad * 4 + r) * 2];
      float lB = ml[(quad * 4 + r) * 2 + 1];
      float m = fmaxf(mrow[r], mB);
      a[r] = __expf(mrow[r] - m);
      bf[r] = __expf(mB - m);
      inv[r] = 1.f / (lrow[r] * a[r] + lB * bf[r]);
    }
    for (int nb = 0; nb < 16; ++nb)
      for (int r = 0; r < 4; ++r) {
        float ob = Om[(quad * 4 + r) * 257 + nb * 16 + m16];
        out[baseQK + (size_t)(q0 + qw * 16 + quad * 4 + r) * DD + nb * 16 +
            m16] = (O[nb][r] * a[r] + ob * bf[r]) * inv[r];
      }
  }
}

extern "C" void kernel_launch(void* const* d_in, const int* in_sizes, int n_in,
                              void* d_out, int out_size, void* d_ws, size_t ws_size,
                              hipStream_t stream) {
  const float* x = (const float*)d_in[0];
  const float* Wq = (const float*)d_in[1];
  const float* Wk = (const float*)d_in[2];
  const float* Wv = (const float*)d_in[3];
  const int* lens = (const int*)d_in[4];
  unsigned short* Qb = (unsigned short*)d_ws;
  unsigned short* Kb = Qb + (size_t)BB * LL * DD;
  unsigned short* VT = Kb + (size_t)BB * LL * DD;
  unsigned short* Wh = VT + (size_t)BB * LL * DD;
  float* out = (float*)d_out;

  wcvt<<<96, 256, 0, stream>>>(Wq, Wk, Wv, Wh);
  proj<<<512, 256, 0, stream>>>(x, Wh, Qb, Kb, VT);
  attn<<<dim3(8, 32), 512, 0, stream>>>(Qb, Kb, VT, lens, out);
}